// Round 9
// baseline (286.304 us; speedup 1.0000x reference)
//
#include <hip/hip_runtime.h>
#include <hip/hip_bf16.h>
#include <cstdint>

// ---------------------------------------------------------------------------
// MAB block (f32 in/out, bf16 internal):
//   Qp=(Q@Wq+bq)*Qm; Kp=(K@Wk+bk)*Km; V=K@Wv+bv
//   S = Qh Kh^T / sqrt(512);  X = exp(exp(S)*Km)*Qm;  A = X/(sum+1e-8)
//   O = Qh + A@Vh;  O = LN0(O);  O = O + relu(O@Wo+bo);  out = LN1(O)
//
// R9..R13: attn 81->72.6 (occupancy, merges); R15: attn T3 2-phase +
//   T21 pre-swizzled K/V staging: 70.6, bank-conflicts 7.3M->3.1M,
//   VALUBusy 50% -> attn near its double-exp VALU floor.
// R16: GEMM-side T3-minimum pipeline (R15's proven pattern):
//   proj_all (both branches) + gemm512 get double-buffered LDS,
//   next-tile DMA issued BEFORE compute, ONE barrier per kt
//   (33 -> 17 barriers/block). Q-branch: 2 ping-pong A-reg sets
//   (compile-time indexed). BK stays 32 (BK=64 would 16-way-conflict
//   the ds_reads; A-operands can't be pre-swizzled -- other readers).
// Buffers: ws ~36MB; d_out upper 16MB = Vt (dead before final LN writes).
// ---------------------------------------------------------------------------

typedef __bf16 bf16;
typedef __bf16 bf16x4 __attribute__((ext_vector_type(4)));
typedef __bf16 bf16x8 __attribute__((ext_vector_type(8)));
typedef float f32x4 __attribute__((ext_vector_type(4)));

#define MFMA16(a, b, c) __builtin_amdgcn_mfma_f32_16x16x32_bf16((a), (b), (c), 0, 0, 0)

#if __has_builtin(__builtin_amdgcn_exp2f)
#define EXP2F(x) __builtin_amdgcn_exp2f(x)
#else
#define EXP2F(x) exp2f(x)
#endif

static __device__ __forceinline__ void async_lds16(const bf16* g, bf16* l) {
  __builtin_amdgcn_global_load_lds(
      (__attribute__((address_space(1))) void*)(void*)g,
      (__attribute__((address_space(3))) void*)l,
      16, 0, 0);
}

// XCD swizzle for 512-block GEMM grids: 4 col-blocks of one row share id&7.
static __device__ __forceinline__ void swz512(int id, long& rowBase, int& colBase) {
  colBase = ((id >> 3) & 3) * 128;
  rowBase = (long)((id & 7) + 8 * (id >> 5)) * 128;
}

// ---------------------------------------------------------------------------
// Batched f32->bf16 conversion args (10 small arrays).
// ---------------------------------------------------------------------------
struct ConvArgs {
  const float* src[10];
  bf16* dst[10];
  int n[10];
};

// ---------------------------------------------------------------------------
// prep: ids 0..255 = weight transpose (4 x 512x512); 256..335 = converts.
// T[n][k] = (bf16)W[k][n].
// ---------------------------------------------------------------------------
__global__ __launch_bounds__(256) void prep(
    const float* __restrict__ Wq, const float* __restrict__ Wk,
    const float* __restrict__ Wv, const float* __restrict__ Wo,
    bf16* __restrict__ Tq, bf16* __restrict__ Tk,
    bf16* __restrict__ Tv, bf16* __restrict__ To, ConvArgs ca) {
  __shared__ bf16 t[64][72];
  const int id = blockIdx.x;
  const int tid = threadIdx.x;
  if (id < 256) {
    const int bx = id & 7, by = (id >> 3) & 7, bz = id >> 6;
    const float* src;
    bf16* dst;
    switch (bz) {
      case 0: src = Wq; dst = Tq; break;
      case 1: src = Wk; dst = Tk; break;
      case 2: src = Wv; dst = Tv; break;
      default: src = Wo; dst = To; break;
    }
    const int n0 = bx * 64;
    const int k0 = by * 64;
    for (int c = tid; c < 512; c += 256) {
      const int row = c >> 3, col = (c & 7) * 8;   // row: k, col: n
      const float* sp = src + (size_t)(k0 + row) * 512 + n0 + col;
      const f32x4 a = *(const f32x4*)sp;
      const f32x4 b = *(const f32x4*)(sp + 4);
      bf16x8 v;
#pragma unroll
      for (int j = 0; j < 4; ++j) { v[j] = (bf16)a[j]; v[j + 4] = (bf16)b[j]; }
      *(bf16x8*)(&t[row][col]) = v;
    }
    __syncthreads();
    for (int c = tid; c < 512; c += 256) {
      const int row = c >> 3, col8 = (c & 7) * 8;  // row: n, col8: k
      bf16x8 v;
#pragma unroll
      for (int j = 0; j < 8; ++j) v[j] = t[col8 + j][row];
      *(bf16x8*)(dst + (size_t)(n0 + row) * 512 + k0 + col8) = v;
    }
  } else {
    const int cid = id - 256;
    const int seg = cid >> 3;
    const int n = ca.n[seg];
    const long i = ((long)(cid & 7) * 256 + tid) * 8;
    if (i >= n) return;
    const float* s = ca.src[seg];
    const f32x4 x0 = *(const f32x4*)(s + i);
    const f32x4 x1 = *(const f32x4*)(s + i + 4);
    bf16x8 o;
#pragma unroll
    for (int j = 0; j < 4; ++j) { o[j] = (bf16)x0[j]; o[j + 4] = (bf16)x1[j]; }
    *(bf16x8*)(ca.dst[seg] + i) = o;
  }
}

// ---------------------------------------------------------------------------
// GEMM (bf16 A): out[M x 512] = epilogue(A @ Bt^T + bias).
// R16: double-buffered LDS, issue-early DMA, one barrier per kt.
// ---------------------------------------------------------------------------
__global__ __launch_bounds__(256, 2) void gemm512(
    const bf16* __restrict__ A, const bf16* __restrict__ Bt,
    const bf16* __restrict__ bias, const bf16* __restrict__ mask,
    const bf16* __restrict__ resid, bf16* __restrict__ out) {
  __shared__ bf16 sA[2][128 * 32];
  __shared__ bf16 sB[2][128 * 32];
  const int tid = threadIdx.x;
  const int lane = tid & 63;
  const int w = tid >> 6;
  const int fm = lane & 15;
  const int fq = lane >> 4;
  long rowBase; int colBase;
  swz512(blockIdx.x, rowBase, colBase);

  f32x4 acc[4][4] = {};

  const int c0 = tid, c1 = tid + 256;
  const int r0 = c0 >> 2, o0 = (c0 & 3) * 8;
  const int r1 = c1 >> 2, o1 = (c1 & 3) * 8;
  const bf16* A0 = A + (rowBase + r0) * 512 + o0;
  const bf16* A1 = A + (rowBase + r1) * 512 + o1;
  const bf16* B0 = Bt + (size_t)(colBase + r0) * 512 + o0;
  const bf16* B1 = Bt + (size_t)(colBase + r1) * 512 + o1;

  const int wr = (w & 1) * 64;
  const int wc = (w >> 1) * 64;

  // prologue: stage tile 0
  async_lds16(A0, sA[0] + c0 * 8);
  async_lds16(A1, sA[0] + c1 * 8);
  async_lds16(B0, sB[0] + c0 * 8);
  async_lds16(B1, sB[0] + c1 * 8);
  __syncthreads();

  for (int kt = 0; kt < 16; ++kt) {
    const int cur = kt & 1;
    if (kt < 15) {                        // issue next tile's DMA now
      const int k1 = (kt + 1) * 32;
      async_lds16(A0 + k1, sA[cur ^ 1] + c0 * 8);
      async_lds16(A1 + k1, sA[cur ^ 1] + c1 * 8);
      async_lds16(B0 + k1, sB[cur ^ 1] + c0 * 8);
      async_lds16(B1 + k1, sB[cur ^ 1] + c1 * 8);
    }
    bf16x8 a[4], b[4];
#pragma unroll
    for (int i = 0; i < 4; ++i)
      a[i] = *(const bf16x8*)(sA[cur] + (wr + i * 16 + fm) * 32 + fq * 8);
#pragma unroll
    for (int j = 0; j < 4; ++j)
      b[j] = *(const bf16x8*)(sB[cur] + (wc + j * 16 + fm) * 32 + fq * 8);
#pragma unroll
    for (int i = 0; i < 4; ++i)
#pragma unroll
      for (int j = 0; j < 4; ++j)
        acc[i][j] = MFMA16(a[i], b[j], acc[i][j]);
    __syncthreads();                      // drains DMA; frees cur for kt+2
  }

  // epilogue; C/D layout: col = lane&15, row = (lane>>4)*4 + r
#pragma unroll
  for (int i = 0; i < 4; ++i) {
#pragma unroll
    for (int r = 0; r < 4; ++r) {
      const long R = rowBase + wr + i * 16 + fq * 4 + r;
      const float mk = mask ? (float)mask[R] : 1.0f;
      const bf16* resrow = resid ? resid + R * 512 : nullptr;
      bf16* outrow = out + R * 512;
#pragma unroll
      for (int j = 0; j < 4; ++j) {
        const int C = colBase + wc + j * 16 + fm;
        float v = acc[i][j][r] + (float)bias[C];
        if (mask) v *= mk;
        if (resid) v = (float)resrow[C] + fmaxf(v, 0.0f);
        outrow[C] = (bf16)v;
      }
    }
  }
}

// ---------------------------------------------------------------------------
// proj_all: ids 0..511 = Q projection (f32 A, fused cvt); 512..1023 =
// fused K/V projection. R16: T3-min pipeline -- dbuf LDS, issue-early
// B-DMA, ping-pong A-reg sets, one barrier/kt.
// Kp/Vt written PRE-SWIZZLED for attn (T21):
//   Kp col = (C&~63) | ((C&63) ^ ((R&7)<<3))
//   Vt kk  = (kk&~63) | ((kk&63) ^ ((C&7)<<3))
// ---------------------------------------------------------------------------
__global__ __launch_bounds__(256, 2) void proj_all(
    const float* __restrict__ Qf, const float* __restrict__ Kf,
    const bf16* __restrict__ Tq, const bf16* __restrict__ Tk,
    const bf16* __restrict__ Tv, const bf16* __restrict__ bq,
    const bf16* __restrict__ bk, const bf16* __restrict__ bv,
    const bf16* __restrict__ Qm, const bf16* __restrict__ Km,
    bf16* __restrict__ Qp, bf16* __restrict__ Kp, bf16* __restrict__ Vt) {
  __shared__ bf16 smem[24576];           // 48KB: carved per branch
  const int tid = threadIdx.x;
  const int lane = tid & 63;
  const int w = tid >> 6;
  const int fm = lane & 15;
  const int fq = lane >> 4;
  const int wr = (w & 1) * 64;
  const int wc = (w >> 1) * 64;
  const int c0 = tid, c1 = tid + 256;
  const int r0 = c0 >> 2, o0 = (c0 & 3) * 8;
  const int r1 = c1 >> 2, o1 = (c1 & 3) * 8;

  if (blockIdx.x < 512) {
    // ---- Q projection: A f32 (reg-cvt ping-pong), B via DMA ----
    long rowBase; int colBase;
    swz512(blockIdx.x, rowBase, colBase);
    f32x4 acc[4][4] = {};
    const float* A0 = Qf + (rowBase + r0) * 512 + o0;
    const float* A1 = Qf + (rowBase + r1) * 512 + o1;
    const bf16* B0 = Tq + (size_t)(colBase + r0) * 512 + o0;
    const bf16* B1 = Tq + (size_t)(colBase + r1) * 512 + o1;
    bf16* bufA[2] = {smem, smem + 4096};
    bf16* bufB[2] = {smem + 8192, smem + 12288};

    auto loadA = [&](int t, f32x4& u0, f32x4& u1, f32x4& v0, f32x4& v1) {
      const int k = t * 32;
      u0 = *(const f32x4*)(A0 + k);
      u1 = *(const f32x4*)(A0 + k + 4);
      v0 = *(const f32x4*)(A1 + k);
      v1 = *(const f32x4*)(A1 + k + 4);
    };
    auto writeA = [&](bf16* dst, const f32x4& u0, const f32x4& u1,
                      const f32x4& v0, const f32x4& v1) {
      bf16x8 va, vb;
#pragma unroll
      for (int j = 0; j < 4; ++j) {
        va[j] = (bf16)u0[j]; va[j + 4] = (bf16)u1[j];
        vb[j] = (bf16)v0[j]; vb[j + 4] = (bf16)v1[j];
      }
      *(bf16x8*)(dst + c0 * 8) = va;
      *(bf16x8*)(dst + c1 * 8) = vb;
    };
    auto stageB = [&](int t, int bb) {
      const int k = t * 32;
      async_lds16(B0 + k, bufB[bb] + c0 * 8);
      async_lds16(B1 + k, bufB[bb] + c1 * 8);
    };
    auto compute = [&](int bb) {
      bf16x8 a[4], b[4];
#pragma unroll
      for (int i = 0; i < 4; ++i)
        a[i] = *(const bf16x8*)(bufA[bb] + (wr + i * 16 + fm) * 32 + fq * 8);
#pragma unroll
      for (int j = 0; j < 4; ++j)
        b[j] = *(const bf16x8*)(bufB[bb] + (wc + j * 16 + fm) * 32 + fq * 8);
#pragma unroll
      for (int i = 0; i < 4; ++i)
#pragma unroll
        for (int j = 0; j < 4; ++j)
          acc[i][j] = MFMA16(a[i], b[j], acc[i][j]);
    };

    f32x4 aX0, aX1, aY0, aY1;  // set X: even tiles
    f32x4 bX0, bX1, bY0, bY1;  // set Y: odd tiles
    loadA(0, aX0, aX1, aY0, aY1);
    writeA(bufA[0], aX0, aX1, aY0, aY1);
    stageB(0, 0);
    loadA(1, bX0, bX1, bY0, bY1);
    __syncthreads();

    for (int kt2 = 0; kt2 < 8; ++kt2) {
      const int kt = kt2 * 2;
      // even iter: compute buf0; fill buf1 with tile kt+1 (set Y)
      stageB(kt + 1, 1);
      writeA(bufA[1], bX0, bX1, bY0, bY1);
      if (kt + 2 < 16) loadA(kt + 2, aX0, aX1, aY0, aY1);
      compute(0);
      __syncthreads();
      // odd iter: compute buf1; fill buf0 with tile kt+2 (set X)
      if (kt + 2 < 16) {
        stageB(kt + 2, 0);
        writeA(bufA[0], aX0, aX1, aY0, aY1);
        if (kt + 3 < 16) loadA(kt + 3, bX0, bX1, bY0, bY1);
      }
      compute(1);
      __syncthreads();
    }

#pragma unroll
    for (int i = 0; i < 4; ++i) {
#pragma unroll
      for (int r = 0; r < 4; ++r) {
        const long R = rowBase + wr + i * 16 + fq * 4 + r;
        const float mk = (float)Qm[R];
        bf16* outrow = Qp + R * 512;
#pragma unroll
        for (int j = 0; j < 4; ++j) {
          const int C = colBase + wc + j * 16 + fm;
          outrow[C] = (bf16)((acc[i][j][r] + (float)bq[C]) * mk);
        }
      }
    }
  } else {
    // ---- fused K/V projection ----
    long rowBase; int colBase;
    swz512(blockIdx.x - 512, rowBase, colBase);
    f32x4 acck[4][4] = {};
    f32x4 accv[4][4] = {};
    const float* A0 = Kf + (rowBase + r0) * 512 + o0;
    const float* A1 = Kf + (rowBase + r1) * 512 + o1;
    const bf16* Bk0 = Tk + (size_t)(colBase + r0) * 512 + o0;
    const bf16* Bk1 = Tk + (size_t)(colBase + r1) * 512 + o1;
    const bf16* Bv0 = Tv + (size_t)(colBase + r0) * 512 + o0;
    const bf16* Bv1 = Tv + (size_t)(colBase + r1) * 512 + o1;
    bf16* bufA[2] = {smem, smem + 4096};
    bf16* bufBk[2] = {smem + 8192, smem + 12288};
    bf16* bufBv[2] = {smem + 16384, smem + 20480};

    auto loadA = [&](int t, f32x4& u0, f32x4& u1, f32x4& v0, f32x4& v1) {
      const int k = t * 32;
      u0 = *(const f32x4*)(A0 + k);
      u1 = *(const f32x4*)(A0 + k + 4);
      v0 = *(const f32x4*)(A1 + k);
      v1 = *(const f32x4*)(A1 + k + 4);
    };
    auto writeA = [&](bf16* dst, const f32x4& u0, const f32x4& u1,
                      const f32x4& v0, const f32x4& v1) {
      bf16x8 va, vb;
#pragma unroll
      for (int j = 0; j < 4; ++j) {
        va[j] = (bf16)u0[j]; va[j + 4] = (bf16)u1[j];
        vb[j] = (bf16)v0[j]; vb[j + 4] = (bf16)v1[j];
      }
      *(bf16x8*)(dst + c0 * 8) = va;
      *(bf16x8*)(dst + c1 * 8) = vb;
    };
    auto stageB = [&](int t, int bb) {
      const int k = t * 32;
      async_lds16(Bk0 + k, bufBk[bb] + c0 * 8);
      async_lds16(Bk1 + k, bufBk[bb] + c1 * 8);
      async_lds16(Bv0 + k, bufBv[bb] + c0 * 8);
      async_lds16(Bv1 + k, bufBv[bb] + c1 * 8);
    };
    auto compute = [&](int bb) {
      bf16x8 a[4], b[4], b2[4];
#pragma unroll
      for (int i = 0; i < 4; ++i)
        a[i] = *(const bf16x8*)(bufA[bb] + (wr + i * 16 + fm) * 32 + fq * 8);
#pragma unroll
      for (int j = 0; j < 4; ++j) {
        b[j] = *(const bf16x8*)(bufBk[bb] + (wc + j * 16 + fm) * 32 + fq * 8);
        b2[j] = *(const bf16x8*)(bufBv[bb] + (wc + j * 16 + fm) * 32 + fq * 8);
      }
#pragma unroll
      for (int i = 0; i < 4; ++i)
#pragma unroll
        for (int j = 0; j < 4; ++j) {
          acck[i][j] = MFMA16(a[i], b[j], acck[i][j]);
          accv[i][j] = MFMA16(a[i], b2[j], accv[i][j]);
        }
    };

    f32x4 aX0, aX1, aY0, aY1;
    f32x4 bX0, bX1, bY0, bY1;
    loadA(0, aX0, aX1, aY0, aY1);
    writeA(bufA[0], aX0, aX1, aY0, aY1);
    stageB(0, 0);
    loadA(1, bX0, bX1, bY0, bY1);
    __syncthreads();

    for (int kt2 = 0; kt2 < 8; ++kt2) {
      const int kt = kt2 * 2;
      stageB(kt + 1, 1);
      writeA(bufA[1], bX0, bX1, bY0, bY1);
      if (kt + 2 < 16) loadA(kt + 2, aX0, aX1, aY0, aY1);
      compute(0);
      __syncthreads();
      if (kt + 2 < 16) {
        stageB(kt + 2, 0);
        writeA(bufA[0], aX0, aX1, aY0, aY1);
        if (kt + 3 < 16) loadA(kt + 3, bX0, bX1, bY0, bY1);
      }
      compute(1);
      __syncthreads();
    }

    const int bidx = (int)(rowBase >> 10);
#pragma unroll
    for (int i = 0; i < 4; ++i) {
#pragma unroll
      for (int r = 0; r < 4; ++r) {
        const long R = rowBase + wr + i * 16 + fq * 4 + r;
        const int rs = (int)(R & 7) << 3;      // attn-tile row swizzle
        const float mk = (float)Km[R];
        bf16* outrow = Kp + R * 512;
#pragma unroll
        for (int j = 0; j < 4; ++j) {
          const int C = colBase + wc + j * 16 + fm;
          const int Cs = (C & ~63) | ((C & 63) ^ rs);
          outrow[Cs] = (bf16)((acck[i][j][r] + (float)bk[C]) * mk);
        }
      }
      // V: transposed store, r -> 4 consecutive kk (8B store), swizzled kk
      const int kkb = (int)(rowBase & 1023) + wr + i * 16 + fq * 4;
#pragma unroll
      for (int j = 0; j < 4; ++j) {
        const int C = colBase + wc + j * 16 + fm;
        const int ds = (C & 7) << 3;
        const int kks = (kkb & ~63) | ((kkb & 63) ^ ds);
        const float bvc = (float)bv[C];
        bf16x4 pv;
#pragma unroll
        for (int r = 0; r < 4; ++r) pv[r] = (bf16)(accv[i][j][r] + bvc);
        bf16* dst =
            Vt + ((size_t)(bidx * 8 + (C >> 6)) * 64 + (C & 63)) * 1024 + kks;
        *(bf16x4*)((void*)dst) = pv;
      }
    }
  }
}

// ---------------------------------------------------------------------------
// Attention (R15, unchanged): 128-q-row blocks, wave owns 32 q-rows.
// T3 2-phase: double-buffered sK/sVt staged via global_load_lds from
// PRE-SWIZZLED Kp/Vt; next tile issued before compute; ONE barrier/kt.
// Reads XOR-swizzled: elem col ^= (row&7)<<3. Km staged once as bf16.
// y = exp2(exp2(s*c1 + C2)*km), C2 = log2(log2e). LDS 52.5KB, 3 blk/CU.
// ---------------------------------------------------------------------------
__global__ __launch_bounds__(256, 3) void attn_kernel(
    bf16* __restrict__ Qp, const bf16* __restrict__ Kp,
    const bf16* __restrict__ Vt, const bf16* __restrict__ Qm,
    const bf16* __restrict__ Km) {
  __shared__ bf16 sK[2][64][64];   // swizzled storage
  __shared__ bf16 sVt[2][64][64];
  __shared__ bf16 sX[4][32][72];   // per-wave [q][kk]
  __shared__ bf16 sKm[1024];       // whole-batch K mask (exact 0/1)
  __shared__ float sL[4][32];

  const int tid = threadIdx.x;
  const int lane = tid & 63;
  const int w = tid >> 6;
  const int fm = lane & 15;
  const int fq = lane >> 4;
  const int id = blockIdx.x;
  const int bh = id & 127;
  const int q0 = (id >> 7) * 128;
  const int b = bh >> 3;
  const int hh = bh & 7;
  const int rot = (id >> 3) & 15;

  bf16* Qbase = Qp + ((long)b * 1024 + q0) * 512 + hh * 64;
  float qm_lane[2];
  qm_lane[0] = (float)Qm[(long)b * 1024 + q0 + w * 32 + fm];
  qm_lane[1] = (float)Qm[(long)b * 1024 + q0 + w * 32 + 16 + fm];

  // loop-invariant Q fragments straight from global: [subtile u][ks]
  bf16x8 qf[2][2];
#pragma unroll
  for (int u = 0; u < 2; ++u)
#pragma unroll
    for (int ks = 0; ks < 2; ++ks)
      qf[u][ks] = *(const bf16x8*)(Qbase + (long)(w * 32 + u * 16 + fm) * 512 +
                                   ks * 32 + fq * 8);

  f32x4 acc_o[2][4] = {};
  float l_lane[2] = {0.f, 0.f};
  const float c1 = 0.063758715f;       // log2(e)/sqrt(512)
  const float C2 = 0.5287663729448977f;  // log2(log2(e))

  const bf16* Vthead = Vt + ((long)b * 8 + hh) * 64 * 1024;  // [d][kk] swz
  const bf16* Kbb = Kp + (long)b * 1024 * 512 + hh * 64;     // swz cols
  const bf16* Kmb = Km + (long)b * 1024;

  const int srow = tid >> 3;           // 0..31
  const int scol = (tid & 7) * 8;
  const int xsw = (fm & 7) << 3;       // read-side swizzle

  // prologue: stage tile 0 + whole Km
  {
    const int kk0 = (rot & 15) * 64;
    const bf16* Kb0 = Kbb + (long)kk0 * 512;
    async_lds16(Kb0 + (long)srow * 512 + scol, &sK[0][0][0] + tid * 8);
    async_lds16(Kb0 + (long)(srow + 32) * 512 + scol,
                &sK[0][0][0] + 2048 + tid * 8);
    async_lds16(Vthead + (long)srow * 1024 + kk0 + scol, &sVt[0][0][0] + tid * 8);
    async_lds16(Vthead + (long)(srow + 32) * 1024 + kk0 + scol,
                &sVt[0][0][0] + 2048 + tid * 8);
    *(bf16x4*)(&sKm[tid * 4]) = *(const bf16x4*)(Kmb + tid * 4);
  }
  __syncthreads();

  for (int kt = 0; kt < 16; ++kt) {
    const int cur = kt & 1;
    // issue next tile's DMA before compute (drains at end-of-kt barrier)
    if (kt < 15) {
      const int kk1 = ((kt + 1 + rot) & 15) * 64;
      const bf16* Kb1 = Kbb + (long)kk1 * 512;
      bf16* dK = &sK[cur ^ 1][0][0];
      bf16* dV = &sVt[cur ^ 1][0][0];
      async_lds16(Kb1 + (long)srow * 512 + scol, dK + tid * 8);
      async_lds16(Kb1 + (long)(srow + 32) * 512 + scol, dK + 2048 + tid * 8);
      async_lds16(Vthead + (long)srow * 1024 + kk1 + scol, dV + tid * 8);
      async_lds16(Vthead + (long)(srow + 32) * 1024 + kk1 + scol,
                  dV + 2048 + tid * 8);
    }
    const int kkT = ((kt + rot) & 15) * 64;

    // S^T: C[kk 64][q 32]; A = K rows (m=kk), B = Q rows (n=q, 2 subtiles)
    f32x4 s_acc[2][4] = {};
#pragma unroll
    for (int ks = 0; ks < 2; ++ks) {
      const int kc = (ks * 32 + fq * 8) ^ xsw;
#pragma unroll
      for (int t = 0; t < 4; ++t) {
        const bf16x8 kf = *(const bf16x8*)(&sK[cur][t * 16 + fm][kc]);
        s_acc[0][t] = MFMA16(kf, qf[0][ks], s_acc[0][t]);
        s_acc[1][t] = MFMA16(kf, qf[1][ks], s_acc[1][t]);
      }
    }
    // softmax: lane holds q=fm (subtile u), kk = t*16 + fq*4 + r
#pragma unroll
    for (int t = 0; t < 4; ++t) {
      const bf16x4 km4 = *(const bf16x4*)(&sKm[kkT + t * 16 + fq * 4]);
      float kmf[4];
#pragma unroll
      for (int r = 0; r < 4; ++r) kmf[r] = (float)km4[r];
#pragma unroll
      for (int u = 0; u < 2; ++u) {
        bf16x4 xp;
#pragma unroll
        for (int r = 0; r < 4; ++r) {
          const float e1L = EXP2F(fmaf(s_acc[u][t][r], c1, C2));
          const float y = EXP2F(e1L * kmf[r]);
          l_lane[u] += y;
          xp[r] = (bf16)y;
        }
        *(bf16x4*)((void*)&sX[w][u * 16 + fm][t * 16 + fq * 4]) = xp;
      }
    }
    // PV: C[q 32][d 64]; A = sX rows (2 subtiles), B = sVt rows (shared)
#pragma unroll
    for (int ks = 0; ks < 2; ++ks) {
      const int kc = (ks * 32 + fq * 8) ^ xsw;
      const bf16x8 xf0 = *(const bf16x8*)(&sX[w][fm][ks * 32 + fq * 8]);
      const bf16x8 xf1 = *(const bf16x8*)(&sX[w][16 + fm][ks * 32 + fq * 8]);
#pragma unroll
      for (int t = 0; t < 4; ++t) {
        const bf16x8 vf = *(const bf16x8*)(&sVt[cur][t * 16 + fm][kc]);
        acc_o[0][t] = MFMA16(xf0, vf, acc_o[0][t]);
        acc_o[1][t] = MFMA16(xf1, vf, acc_o[1][t]);
      }
    }
    __syncthreads();   // drains next-tile DMA; frees cur buf for kt+2
  }

  // per-q Y-sums
#pragma unroll
  for (int u = 0; u < 2; ++u) {
    l_lane[u] += __shfl_xor(l_lane[u], 16);
    l_lane[u] += __shfl_xor(l_lane[u], 32);
    if (fq == 0) sL[w][u * 16 + fm] = l_lane[u];
  }
  __syncthreads();

  // epilogue: lane holds q = u*16 + fq*4 + r, d = t*16 + fm (PV C-layout)
#pragma unroll
  for (int u = 0; u < 2; ++u) {
#pragma unroll
    for (int t = 0; t < 4; ++t) {
#pragma unroll
      for (int r = 0; r < 4; ++r) {
        const int qr = w * 32 + u * 16 + fq * 4 + r;
        const int dc = t * 16 + fm;
        const float qm_r = __shfl(qm_lane[u], fq * 4 + r, 64);
        const float li = 1.0f / (qm_r * sL[w][u * 16 + fq * 4 + r] + 1e-8f);
        const float val =
            (float)Qbase[(long)qr * 512 + dc] + qm_r * acc_o[u][t][r] * li;
        Qbase[(long)qr * 512 + dc] = (bf16)val;
      }
    }
  }
}

// ---------------------------------------------------------------------------
// LayerNorm (bf16 -> bf16). One wave per row. In-place safe.
// ---------------------------------------------------------------------------
__global__ __launch_bounds__(256) void lnorm(
    const bf16* __restrict__ X, const bf16* __restrict__ g,
    const bf16* __restrict__ bb, bf16* __restrict__ out) {
  const int row = blockIdx.x * 4 + (threadIdx.x >> 6);
  const int lane = threadIdx.x & 63;
  const bf16x8 v = *(const bf16x8*)(X + (size_t)row * 512 + lane * 8);
  float x[8], s = 0.f, ss = 0.f;
#pragma unroll
  for (int j = 0; j < 8; ++j) {
    x[j] = (float)v[j];
    s += x[j];
    ss += x[j] * x[j];
  }
#pragma unroll
  for (int m = 1; m < 64; m <<= 1) {
    s += __shfl_xor(s, m);
    ss += __shfl_xor(ss, m);
  }
  const float mean = s * (1.0f / 512.0f);
  const float var = ss * (1.0f / 512.0f) - mean * mean;
  const float rstd = 1.0f / sqrtf(var + 1e-5f);
  const bf16x8 gv = *(const bf16x8*)(g + lane * 8);
  const bf16x8 bv = *(const bf16x8*)(bb + lane * 8);
  bf16x8 o;
#pragma unroll
  for (int j = 0; j < 8; ++j)
    o[j] = (bf16)((x[j] - mean) * rstd * (float)gv[j] + (float)bv[j]);
  *(bf16x8*)(out + (size_t)row * 512 + lane * 8) = o;
}

// ---------------------------------------------------------------------------
// Final LayerNorm: bf16 in, f32 out.
// ---------------------------------------------------------------------------
__global__ __launch_bounds__(256) void lnorm_out(
    const bf16* __restrict__ X, const bf16* __restrict__ g,
    const bf16* __restrict__ bb, float* __restrict__ out) {
  const int row = blockIdx.x * 4 + (threadIdx.x >> 6);
  const int lane = threadIdx.x & 63;
  const bf16x8 v = *(const bf16x8*)(X + (size_t)row * 512 + lane * 8);
  float x[8], s = 0.f, ss = 0.f;
#pragma unroll
  for (int j = 0; j < 8; ++j) {
    x[j] = (float)v[j];
    s += x[j];
    ss += x[j] * x[j];
  }
#pragma unroll
  for (int m = 1; m < 64; m <<= 1) {
    s += __shfl_xor(s, m);
    ss += __shfl_xor(ss, m);
  }
  const float mean = s * (1.0f / 512.0f);
  const float var = ss * (1.0f / 512.0f) - mean * mean;
  const float rstd = 1.0f / sqrtf(var + 1e-5f);
  const bf16x8 gv = *(const bf16x8*)(g + lane * 8);
  const bf16x8 bv = *(const bf16x8*)(bb + lane * 8);
  f32x4 a, c;
#pragma unroll
  for (int j = 0; j < 4; ++j) {
    a[j] = (x[j] - mean) * rstd * (float)gv[j] + (float)bv[j];
    c[j] = (x[j + 4] - mean) * rstd * (float)gv[j + 4] + (float)bv[j + 4];
  }
  float* fo = out + (size_t)row * 512 + lane * 8;
  *(f32x4*)fo = a;
  *(f32x4*)(fo + 4) = c;
}

// ---------------------------------------------------------------------------
extern "C" void kernel_launch(void* const* d_in, const int* in_sizes, int n_in,
                              void* d_out, int out_size, void* d_ws, size_t ws_size,
                              hipStream_t stream) {
  (void)in_sizes; (void)n_in; (void)out_size; (void)ws_size;
  const float* Q = (const float*)d_in[0];
  const float* K = (const float*)d_in[1];

  bf16* ws = (bf16*)d_ws;
  const long W2 = 512L * 512;
  const long MN = 16384L * 512;
  bf16* Tq = ws;                           // 4 transposed bf16 weights: 2MB
  bf16* Tk = Tq + W2;
  bf16* Tv = Tk + W2;
  bf16* To = Tv + W2;
  bf16* sm = To + W2;                      // 8 x 512 smalls
  bf16* cQm = sm + 8 * 512;                // 16384
  bf16* cKm = cQm + 16384;                 // 16384
  bf16* Qp = cKm + 16384;                  // 16MB
  bf16* Kp = Qp + MN;                      // 16MB
  bf16* Vt = (bf16*)d_out + MN;            // V^T in d_out upper 16MB

  bf16* cbq = sm + 0 * 512;
  bf16* cbk = sm + 1 * 512;
  bf16* cbv = sm + 2 * 512;
  bf16* cbo = sm + 3 * 512;
  bf16* cg0 = sm + 4 * 512;
  bf16* cb0 = sm + 5 * 512;
  bf16* cg1 = sm + 6 * 512;
  bf16* cb1 = sm + 7 * 512;

  ConvArgs ca;
  ca.src[0] = (const float*)d_in[2];  ca.dst[0] = cQm; ca.n[0] = 16384;
  ca.src[1] = (const float*)d_in[3];  ca.dst[1] = cKm; ca.n[1] = 16384;
  ca.src[2] = (const float*)d_in[5];  ca.dst[2] = cbq; ca.n[2] = 512;
  ca.src[3] = (const float*)d_in[7];  ca.dst[3] = cbk; ca.n[3] = 512;
  ca.src[4] = (const float*)d_in[9];  ca.dst[4] = cbv; ca.n[4] = 512;
  ca.src[5] = (const float*)d_in[11]; ca.dst[5] = cbo; ca.n[5] = 512;
  ca.src[6] = (const float*)d_in[12]; ca.dst[6] = cg0; ca.n[6] = 512;
  ca.src[7] = (const float*)d_in[13]; ca.dst[7] = cb0; ca.n[7] = 512;
  ca.src[8] = (const float*)d_in[14]; ca.dst[8] = cg1; ca.n[8] = 512;
  ca.src[9] = (const float*)d_in[15]; ca.dst[9] = cb1; ca.n[9] = 512;

  prep<<<336, 256, 0, stream>>>(
      (const float*)d_in[4], (const float*)d_in[6],
      (const float*)d_in[8], (const float*)d_in[10], Tq, Tk, Tv, To, ca);

  proj_all<<<1024, 256, 0, stream>>>(Q, K, Tq, Tk, Tv, cbq, cbk, cbv,
                                     cQm, cKm, Qp, Kp, Vt);

  attn_kernel<<<1024, 256, 0, stream>>>(Qp, Kp, Vt, cQm, cKm);

  lnorm<<<4096, 256, 0, stream>>>(Qp, cg0, cb0, Qp);
  gemm512<<<512, 256, 0, stream>>>(Qp, To, cbo, nullptr, Qp, Kp);
  lnorm_out<<<4096, 256, 0, stream>>>(Kp, cg1, cb1, (float*)d_out);
}